// Round 22
// baseline (51.349 us; speedup 1.0000x reference)
//
#include <hip/hip_runtime.h>

#define L_SEQ 1024
#define NB 8
#define NM 64
#define LM (L_SEQ * NM)    // 65536
#define BLM (NB * LM)      // 524288
#define RS8 0.35355339059327373f
#define LOG2E 1.4426950408889634f

typedef unsigned short u16;
typedef unsigned int u32;
typedef __attribute__((ext_vector_type(8))) short short8;
typedef __attribute__((ext_vector_type(4))) float f32x4;
typedef __attribute__((ext_vector_type(16))) float f32x16;
typedef __attribute__((ext_vector_type(8))) u16 us8;

__device__ __forceinline__ float wredsum(float v) {
#pragma unroll
    for (int off = 32; off; off >>= 1) v += __shfl_xor(v, off);
    return v;
}

__device__ __forceinline__ u16 f2bf(float f) {
    u32 u = __float_as_uint(f);
    u32 r = (u + 0x7FFFu + ((u >> 16) & 1u)) >> 16;
    return (u16)r;
}
__device__ __forceinline__ float bf2f(u16 u) {
    return __uint_as_float((u32)u << 16);
}
// packed RNE f32->bf16 pair (1 VALU op)
__device__ __forceinline__ u32 cvtpk(float lo, float hi) {
    u32 r;
    asm("v_cvt_pk_bf16_f32 %0, %1, %2" : "=v"(r) : "v"(lo), "v"(hi));
    return r;
}

// direct global->LDS DMA, 16 B per lane; dest = lds_base + lane*16 (wave-uniform base)
__device__ __forceinline__ void gll16(const u16* g, u16* l) {
    __builtin_amdgcn_global_load_lds(
        (const __attribute__((address_space(1))) void*)g,
        (__attribute__((address_space(3))) void*)l,
        16, 0, 0);
}

// ---------------- Prep: W fp32 -> bf16 (same layout); x[b][k][m] -> xT[b][m][k] bf16 ----------------
__global__ __launch_bounds__(256) void prep_kernel(
        const float* __restrict__ x, const float* __restrict__ Wq,
        const float* __restrict__ Wk, const float* __restrict__ Wv,
        u16* __restrict__ Wbf, u16* __restrict__ xT) {
    const int bx = blockIdx.x;
    const int tid = threadIdx.x;
    if (bx < 1536) {                       // W convert: 3 x 512 blocks x 2048 elements
        const int w = bx >> 9;
        const int blk = bx & 511;
        const float* W = (w == 0) ? Wq : (w == 1) ? Wk : Wv;
        const size_t base = (size_t)blk * 2048 + (size_t)tid * 8;
        float4 f0 = *(const float4*)&W[base];
        float4 f1 = *(const float4*)&W[base + 4];
        us8 o;
        o[0] = f2bf(f0.x); o[1] = f2bf(f0.y); o[2] = f2bf(f0.z); o[3] = f2bf(f0.w);
        o[4] = f2bf(f1.x); o[5] = f2bf(f1.y); o[6] = f2bf(f1.z); o[7] = f2bf(f1.w);
        *(us8*)&Wbf[(size_t)w * 1048576 + base] = o;
    } else {                               // x transpose: 128 blocks (b, ktile)
        const int blk = bx - 1536;
        const int b = blk >> 4, kt = blk & 15;
        __shared__ float T[64][65];
        const int r16 = tid >> 4, c4 = (tid & 15) * 4;
#pragma unroll
        for (int s = 0; s < 4; s++) {
            int r = r16 + s * 16;
            *(float4*)&T[r][c4] = *(const float4*)&x[((size_t)b * L_SEQ + kt * 64 + r) * NM + c4];
        }
        __syncthreads();
        const int m = tid >> 2;
#pragma unroll
        for (int s = 0; s < 2; s++) {
            int c = (tid & 3) * 2 + s;
            int k0 = c * 8;
            us8 o;
#pragma unroll
            for (int j = 0; j < 8; j++) o[j] = f2bf(T[k0 + j][m]);
            *(us8*)&xT[((size_t)b * NM + m) * L_SEQ + kt * 64 + k0] = o;
        }
    }
}

// ---------------- Projection via MFMA, K-split x4, global_load_lds staging (round-16 form) --------
__global__ __launch_bounds__(256) void proj_mfma(
        const u16* __restrict__ Wbf, const u16* __restrict__ xT,
        u16* __restrict__ H, u16* __restrict__ VtG) {
    const int b  = blockIdx.x;   // 8 (fastest: consecutive blocks share the W tile in L2)
    const int it = blockIdx.y;   // 32 row tiles
    const int w  = blockIdx.z;   // 3
    const int tid = threadIdx.x;
    const int wv = tid >> 6, l = tid & 63;

    __shared__ __align__(16) u16 Ab[4][2048];   // per-wave [32 rows][64 k] swizzled
    __shared__ __align__(16) u16 Bb[4][4096];   // per-wave [64 m][64 k] swizzled; reused as fp32 partials

    const u16* As = Wbf + (size_t)w * 1048576 + (size_t)(it * 32) * L_SEQ;
    const u16* Bs = xT + (size_t)b * (NM * L_SEQ);

    const int soff = (l >> 3) * L_SEQ + (((l & 7) ^ (l >> 3)) * 8);

    f32x4 acc[2][4];
#pragma unroll
    for (int i = 0; i < 2; i++)
#pragma unroll
        for (int j = 0; j < 4; j++) acc[i][j] = (f32x4){0.f, 0.f, 0.f, 0.f};

#define ISSUE(kt) do { \
    _Pragma("unroll") for (int ti = 0; ti < 4; ti++) \
        gll16(&As[(size_t)ti * 8192 + soff + (kt) * 64], &Ab[wv][ti * 512]); \
    _Pragma("unroll") for (int ti = 0; ti < 8; ti++) \
        gll16(&Bs[(size_t)ti * 8192 + soff + (kt) * 64], &Bb[wv][ti * 512]); \
} while (0)

    const int frow = l & 15;
    const int fg = l >> 4;
    const int lx = l & 7;
    const int kt0 = wv * 4;

    ISSUE(kt0);
    asm volatile("s_waitcnt vmcnt(0)" ::: "memory");
    __builtin_amdgcn_sched_barrier(0);

    for (int ii = 0; ii < 4; ++ii) {
        short8 af[2][2], bf[2][4];
#pragma unroll
        for (int ks = 0; ks < 2; ++ks) {
            const int ch = ((ks * 4 + fg) ^ lx) * 8;
            af[ks][0] = *(const short8*)&Ab[wv][frow * 64 + ch];
            af[ks][1] = *(const short8*)&Ab[wv][(16 + frow) * 64 + ch];
#pragma unroll
            for (int cg = 0; cg < 4; ++cg)
                bf[ks][cg] = *(const short8*)&Bb[wv][(cg * 16 + frow) * 64 + ch];
        }
        asm volatile("s_waitcnt lgkmcnt(0)" ::: "memory");   // frags in VGPRs before DMA overwrite
        __builtin_amdgcn_sched_barrier(0);
        if (ii < 3) ISSUE(kt0 + ii + 1);                     // DMAs fly during MFMAs
#pragma unroll
        for (int ks = 0; ks < 2; ++ks)
#pragma unroll
            for (int cg = 0; cg < 4; ++cg) {
                acc[0][cg] = __builtin_amdgcn_mfma_f32_16x16x32_bf16(af[ks][0], bf[ks][cg], acc[0][cg], 0, 0, 0);
                acc[1][cg] = __builtin_amdgcn_mfma_f32_16x16x32_bf16(af[ks][1], bf[ks][cg], acc[1][cg], 0, 0, 0);
            }
        if (ii < 3) {
            asm volatile("s_waitcnt vmcnt(0)" ::: "memory"); // next tile landed before its ds_reads
            __builtin_amdgcn_sched_barrier(0);
        }
    }
#undef ISSUE

    // ---- reduce 4 K-partials through Bb (fp32 view), then parallel epilogue ----
    __syncthreads();
    float* Pp = (float*)&Bb[0][0];
#pragma unroll
    for (int rg = 0; rg < 2; ++rg)
#pragma unroll
        for (int cg = 0; cg < 4; ++cg)
#pragma unroll
            for (int r = 0; r < 4; ++r)
                Pp[wv * 2048 + (rg * 16 + fg * 4 + r) * 64 + cg * 16 + frow] = acc[rg][cg][r];
    __syncthreads();

    {
        const int row = wv * 8 + (l >> 3);
        const int c8  = (l & 7) * 8;
        f32x4 s0 = *(const f32x4*)&Pp[row * 64 + c8];
        f32x4 s1 = *(const f32x4*)&Pp[row * 64 + c8 + 4];
#pragma unroll
        for (int p = 1; p < 4; ++p) {
            f32x4 t0 = *(const f32x4*)&Pp[p * 2048 + row * 64 + c8];
            f32x4 t1 = *(const f32x4*)&Pp[p * 2048 + row * 64 + c8 + 4];
            s0 += t0; s1 += t1;
        }
        const int iq = it * 32 + row;
        const int c  = c8 >> 3;
        us8 o;
        o[0] = f2bf(s0[0]); o[1] = f2bf(s0[1]); o[2] = f2bf(s0[2]); o[3] = f2bf(s0[3]);
        o[4] = f2bf(s1[0]); o[5] = f2bf(s1[1]); o[6] = f2bf(s1[2]); o[7] = f2bf(s1[3]);
        u16* dst = H + (size_t)w * 524288 + (size_t)b * 65536;
        *(us8*)&dst[((size_t)c * L_SEQ + iq) * 8] = o;
        if (w == 2) {
#pragma unroll
            for (int j = 0; j < 8; ++j)
                VtG[((size_t)(b * 8 + c) * 8 + j) * L_SEQ + iq] = o[j];
        }
    }
}

// ---------------- attn 32x32 chunk: 32 keys x 32 queries, permlane P-exchange (no LDS) ----------
// S^T = mfma_32x32x16(A=K[32k][d8 pad16], B=Q): lane holds col q=l&31, rows ko(r)=(r&3)+8(r>>2)+4*l5.
// PV B-frag (keys 8*l5..+8 per 16-key sub-chunk) = 2 permlane32_swap per sub-chunk:
// (u0,u2)=swap(W0a,W1a), (u1,u3)=swap(W0b,W1b)  [swap exchanges vdst.hi <-> vsrc.lo].
__device__ __forceinline__ void achunk32(
        const u16* __restrict__ Kl, const u16* __restrict__ Vtl,
        const short8& qf, int kb, int l31, int l5, bool diag,
        f32x16& oacc, float& lsum) {
    const short8 z8 = {0, 0, 0, 0, 0, 0, 0, 0};
    const f32x16 cz = {0.f, 0.f, 0.f, 0.f, 0.f, 0.f, 0.f, 0.f,
                       0.f, 0.f, 0.f, 0.f, 0.f, 0.f, 0.f, 0.f};
    short8 kf = z8;
    if (l5 == 0) kf = *(const short8*)&Kl[(kb + l31) * 8];
    f32x16 dS = __builtin_amdgcn_mfma_f32_32x32x16_bf16(kf, qf, cz, 0, 0, 0);
    float p[16];
#pragma unroll
    for (int r = 0; r < 16; ++r) {
        p[r] = exp2f(dS[r]);
        if (diag) {
            const int ko = (r & 3) + 8 * (r >> 2) + 4 * l5;
            p[r] = (ko <= l31) ? p[r] : 0.f;
        }
        lsum += p[r];
    }
    u32 W0a = cvtpk(p[0], p[1]),   W0b = cvtpk(p[2], p[3]);
    u32 W1a = cvtpk(p[4], p[5]),   W1b = cvtpk(p[6], p[7]);
    u32 W2a = cvtpk(p[8], p[9]),   W2b = cvtpk(p[10], p[11]);
    u32 W3a = cvtpk(p[12], p[13]), W3b = cvtpk(p[14], p[15]);
    asm volatile("v_permlane32_swap_b32 %0, %1" : "+v"(W0a), "+v"(W1a));
    asm volatile("v_permlane32_swap_b32 %0, %1" : "+v"(W0b), "+v"(W1b));
    asm volatile("v_permlane32_swap_b32 %0, %1" : "+v"(W2a), "+v"(W3a));
    asm volatile("v_permlane32_swap_b32 %0, %1" : "+v"(W2b), "+v"(W3b));
    union { u32 u[4]; short8 s; } f1, f2;
    f1.u[0] = W0a; f1.u[1] = W0b; f1.u[2] = W1a; f1.u[3] = W1b;
    f2.u[0] = W2a; f2.u[1] = W2b; f2.u[2] = W3a; f2.u[3] = W3b;
    short8 vf1 = z8, vf2 = z8;
    if (l31 < 8) {
        vf1 = *(const short8*)&Vtl[l31 * 1032 + kb + 8 * l5];
        vf2 = *(const short8*)&Vtl[l31 * 1032 + kb + 8 * l5 + 16];
    }
    oacc = __builtin_amdgcn_mfma_f32_32x32x16_bf16(vf1, f1.s, oacc, 0, 0, 0);
    oacc = __builtin_amdgcn_mfma_f32_32x32x16_bf16(vf2, f2.s, oacc, 0, 0, 0);
}

// ---------------- MFMA attention 32x32 (512 blocks) + out2 (8 blocks), one launch ----------------
// Block u<512: sg = 7-(u&7) (big blocks first), head (c,b); wave wv owns query slice
// sp = 4*sg+wv (32 q), nch = sp+1 chunks (last diagonal). kend = 128*(sg+1).
__global__ __launch_bounds__(256) void attn_mfma(
        const u16* __restrict__ H, const u16* __restrict__ VtG,
        const float* __restrict__ x, const float* __restrict__ pm,
        float* __restrict__ out) {
    const int u = blockIdx.x;    // 0..519
    const int tid = threadIdx.x;
    const int wv = tid >> 6, lane = tid & 63;

    __shared__ __align__(16) u16 Kl[8192];          // [1024 keys][8 d] bf16
    __shared__ __align__(16) u16 Vtl[8 * 1032];     // [8 d][1024+8 keys] bf16 (padded rows)

    if (u < 512) {
        const int sg = 7 - (u & 7);
        const int c = (u >> 3) & 7, b = u >> 6;
        const int l31 = lane & 31, l5 = lane >> 5;
        const int sp = 4 * sg + wv;          // query slice 0..31
        const int qbase = 32 * sp;
        const int nch = sp + 1;
        const int kend = 128 * (sg + 1);     // keys staged (covers slice 4sg+3)

        const size_t hoff = (size_t)(b * 8 + c) * 8192;
        const u16* HQ = H + hoff;
        const u16* HK = H + 524288 + hoff;

        // stage K rows via direct DMA (16 B/lane, linear dest)
        for (int k = tid; k < kend; k += 256)
            gll16(&HK[(size_t)k * 8], &Kl[k * 8]);
        // stage V^T rows (padded stride -> reg-staged)
        {
            const int vd = tid >> 5;                    // 0..7
            const u16* src = VtG + ((size_t)(b * 8 + c) * 8 + vd) * L_SEQ;
            for (int k8 = (tid & 31) * 8; k8 < kend; k8 += 256)
                *(us8*)&Vtl[vd * 1032 + k8] = *(const us8*)&src[k8];
        }

        // Q fragment: col q = qbase + l31; l5=0 lanes carry d0..7 (scaled), l5=1 zero-pad
        const int q = qbase + l31;
        short8 qf = {0, 0, 0, 0, 0, 0, 0, 0};
        {
            us8 qv = *(const us8*)&HQ[(size_t)q * 8];
            if (l5 == 0) {
                const float sc = RS8 * LOG2E;
#pragma unroll
                for (int j = 0; j < 8; j++) qf[j] = (short)f2bf(bf2f(qv[j]) * sc);
            }
        }

        __syncthreads();    // drains vmcnt (DMA) + lgkm before any LDS read

        f32x16 oacc = {0.f, 0.f, 0.f, 0.f, 0.f, 0.f, 0.f, 0.f,
                       0.f, 0.f, 0.f, 0.f, 0.f, 0.f, 0.f, 0.f};
        float lsum = 0.f;
        for (int ch = 0; ch < nch - 1; ++ch)
            achunk32(Kl, Vtl, qf, ch * 32, l31, l5, false, oacc, lsum);
        achunk32(Kl, Vtl, qf, (nch - 1) * 32, l31, l5, true, oacc, lsum);

        lsum += __shfl_xor(lsum, 32);        // lanes (l31,0)/(l31,1) share query column

        // O^T regs 0-3 = d {0..3}+4*l5 for col q; epilogue: out = x + (qm/l)*O
        const float qm = pm[b * L_SEQ + q];
        const float r8 = qm / lsum;          // qm==0 -> out = x exactly
        const size_t off = (size_t)b * LM + (size_t)q * NM + c * 8 + 4 * l5;
        float4 xv = *(const float4*)&x[off];
        float4 o = make_float4(fmaf(oacc[0], r8, xv.x), fmaf(oacc[1], r8, xv.y),
                               fmaf(oacc[2], r8, xv.z), fmaf(oacc[3], r8, xv.w));
        *(float4*)&out[off] = o;
    } else {
        // ---------------- out2: attention[b][k] = qm(b,1023)/8 * sum_c softmax_row_c[k] ----------
        const int b = u - 512;
        float* red = (float*)Kl;
        const float qm = pm[b * L_SEQ + 1023];
        const float sc = RS8 * LOG2E;
        float acc[4] = {0.f, 0.f, 0.f, 0.f};
        float* out2 = out + BLM;
        for (int cc = 0; cc < 8; cc++) {
            const size_t hoff = (size_t)(b * 8 + cc) * 8192;
            us8 qv = *(const us8*)&H[hoff + (size_t)1023 * 8];
            const float q0 = bf2f(qv[0]) * sc, q1 = bf2f(qv[1]) * sc;
            const float q2 = bf2f(qv[2]) * sc, q3 = bf2f(qv[3]) * sc;
            const float q4 = bf2f(qv[4]) * sc, q5 = bf2f(qv[5]) * sc;
            const float q6 = bf2f(qv[6]) * sc, q7 = bf2f(qv[7]) * sc;
            const u16* Kg = H + 524288 + hoff;
            float p[4];
            float ts = 0.f;
#pragma unroll
            for (int i = 0; i < 4; i++) {
                int k = tid + 256 * i;
                us8 kv = *(const us8*)&Kg[(size_t)k * 8];
                float sa = fmaf(q0, bf2f(kv[0]), fmaf(q1, bf2f(kv[1]), fmaf(q2, bf2f(kv[2]), q3 * bf2f(kv[3]))));
                float sb = fmaf(q4, bf2f(kv[4]), fmaf(q5, bf2f(kv[5]), fmaf(q6, bf2f(kv[6]), q7 * bf2f(kv[7]))));
                p[i] = exp2f(sa + sb);
                ts += p[i];
            }
            ts = wredsum(ts);
            if (lane == 0) red[wv] = ts;
            __syncthreads();
            const float inv = 0.125f / (red[0] + red[1] + red[2] + red[3]);
            __syncthreads();
#pragma unroll
            for (int i = 0; i < 4; i++) acc[i] = fmaf(p[i], inv, acc[i]);
        }
#pragma unroll
        for (int i = 0; i < 4; i++) out2[b * L_SEQ + tid + 256 * i] = acc[i] * qm;
    }
}

extern "C" void kernel_launch(void* const* d_in, const int* in_sizes, int n_in,
                              void* d_out, int out_size, void* d_ws, size_t ws_size,
                              hipStream_t stream) {
    const float* x  = (const float*)d_in[0];
    const float* pm = (const float*)d_in[1];
    const float* Wq = (const float*)d_in[2];
    const float* Wk = (const float*)d_in[3];
    const float* Wv = (const float*)d_in[4];

    u16* H    = (u16*)d_ws;                              // 3 MB bf16 head-major Q,K,V
    u16* Wbf  = (u16*)((char*)d_ws + 3145728);           // 6 MB bf16 W[3][1024][1024]
    u16* xT   = (u16*)((char*)d_ws + 9437184);           // 1 MB bf16 xT[8][64][1024]
    u16* VtG  = (u16*)((char*)d_ws + 10485760);          // 1 MB bf16 Vt[64 heads][8][1024]
    float* out = (float*)d_out;                          // [8,1024,64] then [8,1024]

    hipLaunchKernelGGL(prep_kernel, dim3(1664), dim3(256), 0, stream, x, Wq, Wk, Wv, Wbf, xT);
    hipLaunchKernelGGL(proj_mfma, dim3(8, 32, 3), dim3(256), 0, stream, Wbf, xT, H, VtG);
    hipLaunchKernelGGL(attn_mfma, dim3(520), dim3(256), 0, stream, H, VtG, x, pm, out);
}

// Round 23
// 44.912 us; speedup vs baseline: 1.1433x; 1.1433x over previous
//
#include <hip/hip_runtime.h>

#define L_SEQ 1024
#define NB 8
#define NM 64
#define LM (L_SEQ * NM)    // 65536
#define BLM (NB * LM)      // 524288
#define RS8 0.35355339059327373f
#define LOG2E 1.4426950408889634f

typedef unsigned short u16;
typedef unsigned int u32;
typedef __attribute__((ext_vector_type(8))) short short8;
typedef __attribute__((ext_vector_type(4))) float f32x4;
typedef __attribute__((ext_vector_type(16))) float f32x16;
typedef __attribute__((ext_vector_type(8))) u16 us8;

__device__ __forceinline__ float wredsum(float v) {
#pragma unroll
    for (int off = 32; off; off >>= 1) v += __shfl_xor(v, off);
    return v;
}

__device__ __forceinline__ u16 f2bf(float f) {
    u32 u = __float_as_uint(f);
    u32 r = (u + 0x7FFFu + ((u >> 16) & 1u)) >> 16;
    return (u16)r;
}
__device__ __forceinline__ float bf2f(u16 u) {
    return __uint_as_float((u32)u << 16);
}
// packed RNE f32->bf16 pair (1 VALU op)
__device__ __forceinline__ u32 cvtpk(float lo, float hi) {
    u32 r;
    asm("v_cvt_pk_bf16_f32 %0, %1, %2" : "=v"(r) : "v"(lo), "v"(hi));
    return r;
}

// direct global->LDS DMA, 16 B per lane; dest = lds_base + lane*16 (wave-uniform base)
__device__ __forceinline__ void gll16(const u16* g, u16* l) {
    __builtin_amdgcn_global_load_lds(
        (const __attribute__((address_space(1))) void*)g,
        (__attribute__((address_space(3))) void*)l,
        16, 0, 0);
}

// ---------------- Prep: W fp32 -> bf16 (same layout); x[b][k][m] -> xT[b][m][k] bf16 ----------------
__global__ __launch_bounds__(256) void prep_kernel(
        const float* __restrict__ x, const float* __restrict__ Wq,
        const float* __restrict__ Wk, const float* __restrict__ Wv,
        u16* __restrict__ Wbf, u16* __restrict__ xT) {
    const int bx = blockIdx.x;
    const int tid = threadIdx.x;
    if (bx < 1536) {                       // W convert: 3 x 512 blocks x 2048 elements
        const int w = bx >> 9;
        const int blk = bx & 511;
        const float* W = (w == 0) ? Wq : (w == 1) ? Wk : Wv;
        const size_t base = (size_t)blk * 2048 + (size_t)tid * 8;
        float4 f0 = *(const float4*)&W[base];
        float4 f1 = *(const float4*)&W[base + 4];
        us8 o;
        o[0] = f2bf(f0.x); o[1] = f2bf(f0.y); o[2] = f2bf(f0.z); o[3] = f2bf(f0.w);
        o[4] = f2bf(f1.x); o[5] = f2bf(f1.y); o[6] = f2bf(f1.z); o[7] = f2bf(f1.w);
        *(us8*)&Wbf[(size_t)w * 1048576 + base] = o;
    } else {                               // x transpose: 128 blocks (b, ktile)
        const int blk = bx - 1536;
        const int b = blk >> 4, kt = blk & 15;
        __shared__ float T[64][65];
        const int r16 = tid >> 4, c4 = (tid & 15) * 4;
#pragma unroll
        for (int s = 0; s < 4; s++) {
            int r = r16 + s * 16;
            *(float4*)&T[r][c4] = *(const float4*)&x[((size_t)b * L_SEQ + kt * 64 + r) * NM + c4];
        }
        __syncthreads();
        const int m = tid >> 2;
#pragma unroll
        for (int s = 0; s < 2; s++) {
            int c = (tid & 3) * 2 + s;
            int k0 = c * 8;
            us8 o;
#pragma unroll
            for (int j = 0; j < 8; j++) o[j] = f2bf(T[k0 + j][m]);
            *(us8*)&xT[((size_t)b * NM + m) * L_SEQ + kt * 64 + k0] = o;
        }
    }
}

// ---------------- Projection via MFMA, K-split x4, global_load_lds staging (round-16 form) --------
__global__ __launch_bounds__(256) void proj_mfma(
        const u16* __restrict__ Wbf, const u16* __restrict__ xT,
        u16* __restrict__ H, u16* __restrict__ VtG) {
    const int b  = blockIdx.x;   // 8 (fastest: consecutive blocks share the W tile in L2)
    const int it = blockIdx.y;   // 32 row tiles
    const int w  = blockIdx.z;   // 3
    const int tid = threadIdx.x;
    const int wv = tid >> 6, l = tid & 63;

    __shared__ __align__(16) u16 Ab[4][2048];   // per-wave [32 rows][64 k] swizzled
    __shared__ __align__(16) u16 Bb[4][4096];   // per-wave [64 m][64 k] swizzled; reused as fp32 partials

    const u16* As = Wbf + (size_t)w * 1048576 + (size_t)(it * 32) * L_SEQ;
    const u16* Bs = xT + (size_t)b * (NM * L_SEQ);

    const int soff = (l >> 3) * L_SEQ + (((l & 7) ^ (l >> 3)) * 8);

    f32x4 acc[2][4];
#pragma unroll
    for (int i = 0; i < 2; i++)
#pragma unroll
        for (int j = 0; j < 4; j++) acc[i][j] = (f32x4){0.f, 0.f, 0.f, 0.f};

#define ISSUE(kt) do { \
    _Pragma("unroll") for (int ti = 0; ti < 4; ti++) \
        gll16(&As[(size_t)ti * 8192 + soff + (kt) * 64], &Ab[wv][ti * 512]); \
    _Pragma("unroll") for (int ti = 0; ti < 8; ti++) \
        gll16(&Bs[(size_t)ti * 8192 + soff + (kt) * 64], &Bb[wv][ti * 512]); \
} while (0)

    const int frow = l & 15;
    const int fg = l >> 4;
    const int lx = l & 7;
    const int kt0 = wv * 4;

    ISSUE(kt0);
    asm volatile("s_waitcnt vmcnt(0)" ::: "memory");
    __builtin_amdgcn_sched_barrier(0);

    for (int ii = 0; ii < 4; ++ii) {
        short8 af[2][2], bf[2][4];
#pragma unroll
        for (int ks = 0; ks < 2; ++ks) {
            const int ch = ((ks * 4 + fg) ^ lx) * 8;
            af[ks][0] = *(const short8*)&Ab[wv][frow * 64 + ch];
            af[ks][1] = *(const short8*)&Ab[wv][(16 + frow) * 64 + ch];
#pragma unroll
            for (int cg = 0; cg < 4; ++cg)
                bf[ks][cg] = *(const short8*)&Bb[wv][(cg * 16 + frow) * 64 + ch];
        }
        asm volatile("s_waitcnt lgkmcnt(0)" ::: "memory");   // frags in VGPRs before DMA overwrite
        __builtin_amdgcn_sched_barrier(0);
        if (ii < 3) ISSUE(kt0 + ii + 1);                     // DMAs fly during MFMAs
#pragma unroll
        for (int ks = 0; ks < 2; ++ks)
#pragma unroll
            for (int cg = 0; cg < 4; ++cg) {
                acc[0][cg] = __builtin_amdgcn_mfma_f32_16x16x32_bf16(af[ks][0], bf[ks][cg], acc[0][cg], 0, 0, 0);
                acc[1][cg] = __builtin_amdgcn_mfma_f32_16x16x32_bf16(af[ks][1], bf[ks][cg], acc[1][cg], 0, 0, 0);
            }
        if (ii < 3) {
            asm volatile("s_waitcnt vmcnt(0)" ::: "memory"); // next tile landed before its ds_reads
            __builtin_amdgcn_sched_barrier(0);
        }
    }
#undef ISSUE

    // ---- reduce 4 K-partials through Bb (fp32 view), then parallel epilogue ----
    __syncthreads();
    float* Pp = (float*)&Bb[0][0];
#pragma unroll
    for (int rg = 0; rg < 2; ++rg)
#pragma unroll
        for (int cg = 0; cg < 4; ++cg)
#pragma unroll
            for (int r = 0; r < 4; ++r)
                Pp[wv * 2048 + (rg * 16 + fg * 4 + r) * 64 + cg * 16 + frow] = acc[rg][cg][r];
    __syncthreads();

    {
        const int row = wv * 8 + (l >> 3);
        const int c8  = (l & 7) * 8;
        f32x4 s0 = *(const f32x4*)&Pp[row * 64 + c8];
        f32x4 s1 = *(const f32x4*)&Pp[row * 64 + c8 + 4];
#pragma unroll
        for (int p = 1; p < 4; ++p) {
            f32x4 t0 = *(const f32x4*)&Pp[p * 2048 + row * 64 + c8];
            f32x4 t1 = *(const f32x4*)&Pp[p * 2048 + row * 64 + c8 + 4];
            s0 += t0; s1 += t1;
        }
        const int iq = it * 32 + row;
        const int c  = c8 >> 3;
        us8 o;
        o[0] = f2bf(s0[0]); o[1] = f2bf(s0[1]); o[2] = f2bf(s0[2]); o[3] = f2bf(s0[3]);
        o[4] = f2bf(s1[0]); o[5] = f2bf(s1[1]); o[6] = f2bf(s1[2]); o[7] = f2bf(s1[3]);
        u16* dst = H + (size_t)w * 524288 + (size_t)b * 65536;
        *(us8*)&dst[((size_t)c * L_SEQ + iq) * 8] = o;
        if (w == 2) {
#pragma unroll
            for (int j = 0; j < 8; ++j)
                VtG[((size_t)(b * 8 + c) * 8 + j) * L_SEQ + iq] = o[j];
        }
    }
}

// ---------------- attn 32x32 chunk (hardware-verified in round 22, byte-identical) ----------
__device__ __forceinline__ void achunk32(
        const u16* __restrict__ Kl, const u16* __restrict__ Vtl,
        const short8& qf, int kb, int l31, int l5, bool diag,
        f32x16& oacc, float& lsum) {
    const short8 z8 = {0, 0, 0, 0, 0, 0, 0, 0};
    const f32x16 cz = {0.f, 0.f, 0.f, 0.f, 0.f, 0.f, 0.f, 0.f,
                       0.f, 0.f, 0.f, 0.f, 0.f, 0.f, 0.f, 0.f};
    short8 kf = z8;
    if (l5 == 0) kf = *(const short8*)&Kl[(kb + l31) * 8];
    f32x16 dS = __builtin_amdgcn_mfma_f32_32x32x16_bf16(kf, qf, cz, 0, 0, 0);
    float p[16];
#pragma unroll
    for (int r = 0; r < 16; ++r) {
        p[r] = exp2f(dS[r]);
        if (diag) {
            const int ko = (r & 3) + 8 * (r >> 2) + 4 * l5;
            p[r] = (ko <= l31) ? p[r] : 0.f;
        }
        lsum += p[r];
    }
    u32 W0a = cvtpk(p[0], p[1]),   W0b = cvtpk(p[2], p[3]);
    u32 W1a = cvtpk(p[4], p[5]),   W1b = cvtpk(p[6], p[7]);
    u32 W2a = cvtpk(p[8], p[9]),   W2b = cvtpk(p[10], p[11]);
    u32 W3a = cvtpk(p[12], p[13]), W3b = cvtpk(p[14], p[15]);
    asm volatile("v_permlane32_swap_b32 %0, %1" : "+v"(W0a), "+v"(W1a));
    asm volatile("v_permlane32_swap_b32 %0, %1" : "+v"(W0b), "+v"(W1b));
    asm volatile("v_permlane32_swap_b32 %0, %1" : "+v"(W2a), "+v"(W3a));
    asm volatile("v_permlane32_swap_b32 %0, %1" : "+v"(W2b), "+v"(W3b));
    union { u32 u[4]; short8 s; } f1, f2;
    f1.u[0] = W0a; f1.u[1] = W0b; f1.u[2] = W1a; f1.u[3] = W1b;
    f2.u[0] = W2a; f2.u[1] = W2b; f2.u[2] = W3a; f2.u[3] = W3b;
    short8 vf1 = z8, vf2 = z8;
    if (l31 < 8) {
        vf1 = *(const short8*)&Vtl[l31 * 1032 + kb + 8 * l5];
        vf2 = *(const short8*)&Vtl[l31 * 1032 + kb + 8 * l5 + 16];
    }
    oacc = __builtin_amdgcn_mfma_f32_32x32x16_bf16(vf1, f1.s, oacc, 0, 0, 0);
    oacc = __builtin_amdgcn_mfma_f32_32x32x16_bf16(vf2, f2.s, oacc, 0, 0, 0);
}

// ---------------- MFMA attention 32x32, pair-balanced (256 blocks) + out2 (8 blocks) ----------------
// Block u<256: (s 0..3, c, b); wave wv owns slice PAIR spLo=4s+wv (0..15) and spHi=31-spLo.
// Chunk total per wave = (spLo+1)+(spHi+1) = 33, uniform for every wave of every block.
__global__ __launch_bounds__(256) void attn_mfma(
        const u16* __restrict__ H, const u16* __restrict__ VtG,
        const float* __restrict__ x, const float* __restrict__ pm,
        float* __restrict__ out) {
    const int u = blockIdx.x;    // 0..263
    const int tid = threadIdx.x;
    const int wv = tid >> 6, lane = tid & 63;

    __shared__ __align__(16) u16 Kl[8192];          // [1024 keys][8 d] bf16
    __shared__ __align__(16) u16 Vtl[8 * 1032];     // [8 d][1024+8 keys] bf16 (padded rows)

    if (u < 256) {
        const int s = u & 3, c = (u >> 2) & 7, b = u >> 5;
        const int l31 = lane & 31, l5 = lane >> 5;
        const int spLo = 4 * s + wv;         // 0..15
        const int spHi = 31 - spLo;          // 16..31
        const int kend = 32 * (32 - 4 * s);  // covers block max slice (wave 0's spHi)

        const size_t hoff = (size_t)(b * 8 + c) * 8192;
        const u16* HQ = H + hoff;
        const u16* HK = H + 524288 + hoff;

        // stage K rows via direct DMA (16 B/lane, linear dest)
        for (int k = tid; k < kend; k += 256)
            gll16(&HK[(size_t)k * 8], &Kl[k * 8]);
        // stage V^T rows (padded stride -> reg-staged)
        {
            const int vd = tid >> 5;                    // 0..7
            const u16* src = VtG + ((size_t)(b * 8 + c) * 8 + vd) * L_SEQ;
            for (int k8 = (tid & 31) * 8; k8 < kend; k8 += 256)
                *(us8*)&Vtl[vd * 1032 + k8] = *(const us8*)&src[k8];
        }

        // Q fragments for both slices (col q = 32*sp + l31; l5=0 lanes carry d0..7 scaled)
        const int qLo = 32 * spLo + l31, qHi = 32 * spHi + l31;
        short8 qfLo = {0, 0, 0, 0, 0, 0, 0, 0};
        short8 qfHi = {0, 0, 0, 0, 0, 0, 0, 0};
        {
            us8 qvLo = *(const us8*)&HQ[(size_t)qLo * 8];
            us8 qvHi = *(const us8*)&HQ[(size_t)qHi * 8];
            if (l5 == 0) {
                const float sc = RS8 * LOG2E;
#pragma unroll
                for (int j = 0; j < 8; j++) {
                    qfLo[j] = (short)f2bf(bf2f(qvLo[j]) * sc);
                    qfHi[j] = (short)f2bf(bf2f(qvHi[j]) * sc);
                }
            }
        }

        __syncthreads();    // drains vmcnt (DMA) + lgkm before any LDS read

        const f32x16 cz = {0.f, 0.f, 0.f, 0.f, 0.f, 0.f, 0.f, 0.f,
                           0.f, 0.f, 0.f, 0.f, 0.f, 0.f, 0.f, 0.f};

#define RUNPASS32(QF, SP, Q) do { \
    f32x16 oacc_ = cz; \
    float lsum_ = 0.f; \
    const int nch_ = (SP) + 1; \
    for (int ch_ = 0; ch_ < nch_ - 1; ++ch_) \
        achunk32(Kl, Vtl, QF, ch_ * 32, l31, l5, false, oacc_, lsum_); \
    achunk32(Kl, Vtl, QF, (nch_ - 1) * 32, l31, l5, true, oacc_, lsum_); \
    lsum_ += __shfl_xor(lsum_, 32); \
    const float qm_ = pm[b * L_SEQ + (Q)]; \
    const float r8_ = qm_ / lsum_; \
    const size_t off_ = (size_t)b * LM + (size_t)(Q) * NM + c * 8 + 4 * l5; \
    float4 xv_ = *(const float4*)&x[off_]; \
    float4 o_ = make_float4(fmaf(oacc_[0], r8_, xv_.x), fmaf(oacc_[1], r8_, xv_.y), \
                            fmaf(oacc_[2], r8_, xv_.z), fmaf(oacc_[3], r8_, xv_.w)); \
    *(float4*)&out[off_] = o_; \
} while (0)

        RUNPASS32(qfLo, spLo, qLo);
        RUNPASS32(qfHi, spHi, qHi);
#undef RUNPASS32
    } else {
        // ---------------- out2: attention[b][k] = qm(b,1023)/8 * sum_c softmax_row_c[k] ----------
        const int b = u - 256;
        float* red = (float*)Kl;
        const float qm = pm[b * L_SEQ + 1023];
        const float sc = RS8 * LOG2E;
        float acc[4] = {0.f, 0.f, 0.f, 0.f};
        float* out2 = out + BLM;
        for (int cc = 0; cc < 8; cc++) {
            const size_t hoff = (size_t)(b * 8 + cc) * 8192;
            us8 qv = *(const us8*)&H[hoff + (size_t)1023 * 8];
            const float q0 = bf2f(qv[0]) * sc, q1 = bf2f(qv[1]) * sc;
            const float q2 = bf2f(qv[2]) * sc, q3 = bf2f(qv[3]) * sc;
            const float q4 = bf2f(qv[4]) * sc, q5 = bf2f(qv[5]) * sc;
            const float q6 = bf2f(qv[6]) * sc, q7 = bf2f(qv[7]) * sc;
            const u16* Kg = H + 524288 + hoff;
            float p[4];
            float ts = 0.f;
#pragma unroll
            for (int i = 0; i < 4; i++) {
                int k = tid + 256 * i;
                us8 kv = *(const us8*)&Kg[(size_t)k * 8];
                float sa = fmaf(q0, bf2f(kv[0]), fmaf(q1, bf2f(kv[1]), fmaf(q2, bf2f(kv[2]), q3 * bf2f(kv[3]))));
                float sb = fmaf(q4, bf2f(kv[4]), fmaf(q5, bf2f(kv[5]), fmaf(q6, bf2f(kv[6]), q7 * bf2f(kv[7]))));
                p[i] = exp2f(sa + sb);
                ts += p[i];
            }
            ts = wredsum(ts);
            if (lane == 0) red[wv] = ts;
            __syncthreads();
            const float inv = 0.125f / (red[0] + red[1] + red[2] + red[3]);
            __syncthreads();
#pragma unroll
            for (int i = 0; i < 4; i++) acc[i] = fmaf(p[i], inv, acc[i]);
        }
#pragma unroll
        for (int i = 0; i < 4; i++) out2[b * L_SEQ + tid + 256 * i] = acc[i] * qm;
    }
}

extern "C" void kernel_launch(void* const* d_in, const int* in_sizes, int n_in,
                              void* d_out, int out_size, void* d_ws, size_t ws_size,
                              hipStream_t stream) {
    const float* x  = (const float*)d_in[0];
    const float* pm = (const float*)d_in[1];
    const float* Wq = (const float*)d_in[2];
    const float* Wk = (const float*)d_in[3];
    const float* Wv = (const float*)d_in[4];

    u16* H    = (u16*)d_ws;                              // 3 MB bf16 head-major Q,K,V
    u16* Wbf  = (u16*)((char*)d_ws + 3145728);           // 6 MB bf16 W[3][1024][1024]
    u16* xT   = (u16*)((char*)d_ws + 9437184);           // 1 MB bf16 xT[8][64][1024]
    u16* VtG  = (u16*)((char*)d_ws + 10485760);          // 1 MB bf16 Vt[64 heads][8][1024]
    float* out = (float*)d_out;                          // [8,1024,64] then [8,1024]

    hipLaunchKernelGGL(prep_kernel, dim3(1664), dim3(256), 0, stream, x, Wq, Wk, Wv, Wbf, xT);
    hipLaunchKernelGGL(proj_mfma, dim3(8, 32, 3), dim3(256), 0, stream, Wbf, xT, H, VtG);
    hipLaunchKernelGGL(attn_mfma, dim3(264), dim3(256), 0, stream, H, VtG, x, pm, out);
}

// Round 24
// 43.889 us; speedup vs baseline: 1.1700x; 1.0233x over previous
//
#include <hip/hip_runtime.h>

#define L_SEQ 1024
#define NB 8
#define NM 64
#define LM (L_SEQ * NM)    // 65536
#define BLM (NB * LM)      // 524288
#define RS8 0.35355339059327373f
#define LOG2E 1.4426950408889634f

typedef unsigned short u16;
typedef unsigned int u32;
typedef __attribute__((ext_vector_type(8))) short short8;
typedef __attribute__((ext_vector_type(4))) float f32x4;
typedef __attribute__((ext_vector_type(8))) u16 us8;

__device__ __forceinline__ float wredsum(float v) {
#pragma unroll
    for (int off = 32; off; off >>= 1) v += __shfl_xor(v, off);
    return v;
}

__device__ __forceinline__ u16 f2bf(float f) {
    u32 u = __float_as_uint(f);
    u32 r = (u + 0x7FFFu + ((u >> 16) & 1u)) >> 16;
    return (u16)r;
}
__device__ __forceinline__ float bf2f(u16 u) {
    return __uint_as_float((u32)u << 16);
}
// packed RNE f32->bf16 pair (1 VALU op)
__device__ __forceinline__ u32 cvtpk(float lo, float hi) {
    u32 r;
    asm("v_cvt_pk_bf16_f32 %0, %1, %2" : "=v"(r) : "v"(lo), "v"(hi));
    return r;
}

// direct global->LDS DMA, 16 B per lane; dest = lds_base + lane*16 (wave-uniform base)
__device__ __forceinline__ void gll16(const u16* g, u16* l) {
    __builtin_amdgcn_global_load_lds(
        (const __attribute__((address_space(1))) void*)g,
        (__attribute__((address_space(3))) void*)l,
        16, 0, 0);
}

// ---------------- Prep: W fp32 -> bf16 (same layout); x[b][k][m] -> xT[b][m][k] bf16 ----------------
__global__ __launch_bounds__(256) void prep_kernel(
        const float* __restrict__ x, const float* __restrict__ Wq,
        const float* __restrict__ Wk, const float* __restrict__ Wv,
        u16* __restrict__ Wbf, u16* __restrict__ xT) {
    const int bx = blockIdx.x;
    const int tid = threadIdx.x;
    if (bx < 1536) {                       // W convert: 3 x 512 blocks x 2048 elements
        const int w = bx >> 9;
        const int blk = bx & 511;
        const float* W = (w == 0) ? Wq : (w == 1) ? Wk : Wv;
        const size_t base = (size_t)blk * 2048 + (size_t)tid * 8;
        float4 f0 = *(const float4*)&W[base];
        float4 f1 = *(const float4*)&W[base + 4];
        us8 o;
        o[0] = f2bf(f0.x); o[1] = f2bf(f0.y); o[2] = f2bf(f0.z); o[3] = f2bf(f0.w);
        o[4] = f2bf(f1.x); o[5] = f2bf(f1.y); o[6] = f2bf(f1.z); o[7] = f2bf(f1.w);
        *(us8*)&Wbf[(size_t)w * 1048576 + base] = o;
    } else {                               // x transpose: 128 blocks (b, ktile)
        const int blk = bx - 1536;
        const int b = blk >> 4, kt = blk & 15;
        __shared__ float T[64][65];
        const int r16 = tid >> 4, c4 = (tid & 15) * 4;
#pragma unroll
        for (int s = 0; s < 4; s++) {
            int r = r16 + s * 16;
            *(float4*)&T[r][c4] = *(const float4*)&x[((size_t)b * L_SEQ + kt * 64 + r) * NM + c4];
        }
        __syncthreads();
        const int m = tid >> 2;
#pragma unroll
        for (int s = 0; s < 2; s++) {
            int c = (tid & 3) * 2 + s;
            int k0 = c * 8;
            us8 o;
#pragma unroll
            for (int j = 0; j < 8; j++) o[j] = f2bf(T[k0 + j][m]);
            *(us8*)&xT[((size_t)b * NM + m) * L_SEQ + kt * 64 + k0] = o;
        }
    }
}

// ---------------- Projection via MFMA, K-split x4, global_load_lds staging (round-16 form) --------
__global__ __launch_bounds__(256) void proj_mfma(
        const u16* __restrict__ Wbf, const u16* __restrict__ xT,
        u16* __restrict__ H, u16* __restrict__ VtG) {
    const int b  = blockIdx.x;   // 8 (fastest: consecutive blocks share the W tile in L2)
    const int it = blockIdx.y;   // 32 row tiles
    const int w  = blockIdx.z;   // 3
    const int tid = threadIdx.x;
    const int wv = tid >> 6, l = tid & 63;

    __shared__ __align__(16) u16 Ab[4][2048];   // per-wave [32 rows][64 k] swizzled
    __shared__ __align__(16) u16 Bb[4][4096];   // per-wave [64 m][64 k] swizzled; reused as fp32 partials

    const u16* As = Wbf + (size_t)w * 1048576 + (size_t)(it * 32) * L_SEQ;
    const u16* Bs = xT + (size_t)b * (NM * L_SEQ);

    const int soff = (l >> 3) * L_SEQ + (((l & 7) ^ (l >> 3)) * 8);

    f32x4 acc[2][4];
#pragma unroll
    for (int i = 0; i < 2; i++)
#pragma unroll
        for (int j = 0; j < 4; j++) acc[i][j] = (f32x4){0.f, 0.f, 0.f, 0.f};

#define ISSUE(kt) do { \
    _Pragma("unroll") for (int ti = 0; ti < 4; ti++) \
        gll16(&As[(size_t)ti * 8192 + soff + (kt) * 64], &Ab[wv][ti * 512]); \
    _Pragma("unroll") for (int ti = 0; ti < 8; ti++) \
        gll16(&Bs[(size_t)ti * 8192 + soff + (kt) * 64], &Bb[wv][ti * 512]); \
} while (0)

    const int frow = l & 15;
    const int fg = l >> 4;
    const int lx = l & 7;
    const int kt0 = wv * 4;

    ISSUE(kt0);
    asm volatile("s_waitcnt vmcnt(0)" ::: "memory");
    __builtin_amdgcn_sched_barrier(0);

    for (int ii = 0; ii < 4; ++ii) {
        short8 af[2][2], bf[2][4];
#pragma unroll
        for (int ks = 0; ks < 2; ++ks) {
            const int ch = ((ks * 4 + fg) ^ lx) * 8;
            af[ks][0] = *(const short8*)&Ab[wv][frow * 64 + ch];
            af[ks][1] = *(const short8*)&Ab[wv][(16 + frow) * 64 + ch];
#pragma unroll
            for (int cg = 0; cg < 4; ++cg)
                bf[ks][cg] = *(const short8*)&Bb[wv][(cg * 16 + frow) * 64 + ch];
        }
        asm volatile("s_waitcnt lgkmcnt(0)" ::: "memory");   // frags in VGPRs before DMA overwrite
        __builtin_amdgcn_sched_barrier(0);
        if (ii < 3) ISSUE(kt0 + ii + 1);                     // DMAs fly during MFMAs
#pragma unroll
        for (int ks = 0; ks < 2; ++ks)
#pragma unroll
            for (int cg = 0; cg < 4; ++cg) {
                acc[0][cg] = __builtin_amdgcn_mfma_f32_16x16x32_bf16(af[ks][0], bf[ks][cg], acc[0][cg], 0, 0, 0);
                acc[1][cg] = __builtin_amdgcn_mfma_f32_16x16x32_bf16(af[ks][1], bf[ks][cg], acc[1][cg], 0, 0, 0);
            }
        if (ii < 3) {
            asm volatile("s_waitcnt vmcnt(0)" ::: "memory"); // next tile landed before its ds_reads
            __builtin_amdgcn_sched_barrier(0);
        }
    }
#undef ISSUE

    // ---- reduce 4 K-partials through Bb (fp32 view), then parallel epilogue ----
    __syncthreads();
    float* Pp = (float*)&Bb[0][0];
#pragma unroll
    for (int rg = 0; rg < 2; ++rg)
#pragma unroll
        for (int cg = 0; cg < 4; ++cg)
#pragma unroll
            for (int r = 0; r < 4; ++r)
                Pp[wv * 2048 + (rg * 16 + fg * 4 + r) * 64 + cg * 16 + frow] = acc[rg][cg][r];
    __syncthreads();

    {
        const int row = wv * 8 + (l >> 3);
        const int c8  = (l & 7) * 8;
        f32x4 s0 = *(const f32x4*)&Pp[row * 64 + c8];
        f32x4 s1 = *(const f32x4*)&Pp[row * 64 + c8 + 4];
#pragma unroll
        for (int p = 1; p < 4; ++p) {
            f32x4 t0 = *(const f32x4*)&Pp[p * 2048 + row * 64 + c8];
            f32x4 t1 = *(const f32x4*)&Pp[p * 2048 + row * 64 + c8 + 4];
            s0 += t0; s1 += t1;
        }
        const int iq = it * 32 + row;
        const int c  = c8 >> 3;
        us8 o;
        o[0] = f2bf(s0[0]); o[1] = f2bf(s0[1]); o[2] = f2bf(s0[2]); o[3] = f2bf(s0[3]);
        o[4] = f2bf(s1[0]); o[5] = f2bf(s1[1]); o[6] = f2bf(s1[2]); o[7] = f2bf(s1[3]);
        u16* dst = H + (size_t)w * 524288 + (size_t)b * 65536;
        *(us8*)&dst[((size_t)c * L_SEQ + iq) * 8] = o;
        if (w == 2) {
#pragma unroll
            for (int j = 0; j < 8; ++j)
                VtG[((size_t)(b * 8 + c) * 8 + j) * L_SEQ + iq] = o[j];
        }
    }
}

// ---------------- MFMA attention (512 blocks, pair-balanced) + out2 (8 blocks FIRST) --------------
// Blocks 0..7: out2 for batch b = u (early launch: stragglers overlap attention body).
// Blocks 8..519: (s,c,b) decode from u-8; query tiles qlo=s, qhi=15-s sequentially per wave.
// K staging via global_load_lds (dest = wave base + lane*16; kend 64-aligned -> wave-granular).
__global__ __launch_bounds__(256) void attn_mfma(
        const u16* __restrict__ H, const u16* __restrict__ VtG,
        const float* __restrict__ x, const float* __restrict__ pm,
        float* __restrict__ out) {
    const int u = blockIdx.x;    // 0..519
    const int tid = threadIdx.x;
    const int wv = tid >> 6, lane = tid & 63;

    __shared__ __align__(16) u16 Kl[8192];          // [1024 keys][8 d] bf16
    __shared__ __align__(16) u16 Vtl[8 * 1032];     // [8 d][1024+8 keys] bf16 (padded rows)

    if (u >= 8) {
        const int ua = u - 8;
        const int s = ua & 7, c = (ua >> 3) & 7, b = ua >> 6;
        const int qtil = lane & 15, g = lane >> 4;

        const size_t hoff = (size_t)(b * 8 + c) * 8192;
        const u16* HQ = H + hoff;
        const u16* HK = H + 524288 + hoff;
        const int qlo = s, qhi = 15 - s;
        const int kend = (qhi + 1) * 64;     // superset: covers both tiles' needs

        // stage K rows via direct DMA (16 B/lane, linear dest)
        for (int k = tid; k < kend; k += 256)
            gll16(&HK[(size_t)k * 8], &Kl[k * 8]);
        // stage V^T rows (padded stride -> reg-staged)
        {
            const int vd = tid >> 5;                    // 0..7
            const u16* src = VtG + ((size_t)(b * 8 + c) * 8 + vd) * L_SEQ;
            for (int k8 = (tid & 31) * 8; k8 < kend; k8 += 256)
                *(us8*)&Vtl[vd * 1032 + k8] = *(const us8*)&src[k8];
        }

        // Q fragments for both tiles (scaled bf16; g=0 lanes carry data, others zero-pad depth)
        short8 qfLo = {0, 0, 0, 0, 0, 0, 0, 0};
        short8 qfHi = {0, 0, 0, 0, 0, 0, 0, 0};
        {
            const float sc = RS8 * LOG2E;
            us8 qvLo = *(const us8*)&HQ[(size_t)(qlo * 64 + wv * 16 + qtil) * 8];
            us8 qvHi = *(const us8*)&HQ[(size_t)(qhi * 64 + wv * 16 + qtil) * 8];
            if (g == 0) {
#pragma unroll
                for (int j = 0; j < 8; j++) {
                    qfLo[j] = (short)f2bf(bf2f(qvLo[j]) * sc);
                    qfHi[j] = (short)f2bf(bf2f(qvHi[j]) * sc);
                }
            }
        }

        __syncthreads();    // drains vmcnt (DMA) + lgkm before any LDS read

        const f32x4 czero = {0.f, 0.f, 0.f, 0.f};
        const short8 z8 = {0, 0, 0, 0, 0, 0, 0, 0};

#define ACHUNK2(QF, ch, PRED) do { \
    const int kb_ = (ch) * 32; \
    short8 kfA_ = z8, kfB_ = z8; \
    if (g == 0) { \
        kfA_ = *(const short8*)&Kl[(kb_ + qtil) * 8]; \
        kfB_ = *(const short8*)&Kl[(kb_ + 16 + qtil) * 8]; \
    } \
    f32x4 dA_ = __builtin_amdgcn_mfma_f32_16x16x32_bf16(kfA_, QF, czero, 0, 0, 0); \
    f32x4 dB_ = __builtin_amdgcn_mfma_f32_16x16x32_bf16(kfB_, QF, czero, 0, 0, 0); \
    float pA_[4], pB_[4]; \
    const int keyA_ = kb_ + 4 * g; \
    _Pragma("unroll") for (int r_ = 0; r_ < 4; r_++) { \
        pA_[r_] = exp2f(dA_[r_]); \
        pB_[r_] = exp2f(dB_[r_]); \
        if (PRED) { \
            pA_[r_] = (keyA_ + r_ <= q_) ? pA_[r_] : 0.f; \
            pB_[r_] = (keyA_ + 16 + r_ <= q_) ? pB_[r_] : 0.f; \
        } \
        lsum_ += pA_[r_] + pB_[r_]; \
    } \
    const u32 A01_ = cvtpk(pA_[0], pA_[1]), A23_ = cvtpk(pA_[2], pA_[3]); \
    const u32 B01_ = cvtpk(pB_[0], pB_[1]), B23_ = cvtpk(pB_[2], pB_[3]); \
    const int src_ = qtil + ((g & 1) << 5); \
    const u32 a0_ = (u32)__shfl((int)A01_, src_, 64); \
    const u32 a1_ = (u32)__shfl((int)A23_, src_, 64); \
    const u32 a2_ = (u32)__shfl((int)A01_, src_ + 16, 64); \
    const u32 a3_ = (u32)__shfl((int)A23_, src_ + 16, 64); \
    const u32 b0_ = (u32)__shfl((int)B01_, src_, 64); \
    const u32 b1_ = (u32)__shfl((int)B23_, src_, 64); \
    const u32 b2_ = (u32)__shfl((int)B01_, src_ + 16, 64); \
    const u32 b3_ = (u32)__shfl((int)B23_, src_ + 16, 64); \
    union { u32 u[4]; short8 s; } pu_; \
    pu_.u[0] = (g < 2) ? a0_ : b0_; \
    pu_.u[1] = (g < 2) ? a1_ : b1_; \
    pu_.u[2] = (g < 2) ? a2_ : b2_; \
    pu_.u[3] = (g < 2) ? a3_ : b3_; \
    short8 vf_ = z8; \
    if (qtil < 8) vf_ = *(const short8*)&Vtl[qtil * 1032 + kb_ + 8 * g]; \
    oacc_ = __builtin_amdgcn_mfma_f32_16x16x32_bf16(vf_, pu_.s, oacc_, 0, 0, 0); \
} while (0)

#define RUNPASS(QF, TILE) do { \
    const int base_ = (TILE) * 64 + wv * 16; \
    const int q_ = base_ + qtil; \
    f32x4 oacc_ = czero; \
    float lsum_ = 0.f; \
    const int nfull_ = (base_ + 1) >> 5; \
    const int nch_ = (base_ + 47) >> 5; \
    for (int ch_ = 0; ch_ < nfull_; ++ch_) ACHUNK2(QF, ch_, false); \
    for (int ch_ = nfull_; ch_ < nch_; ++ch_) ACHUNK2(QF, ch_, true); \
    lsum_ += __shfl_xor(lsum_, 16); \
    lsum_ += __shfl_xor(lsum_, 32); \
    if (g < 2) { \
        const float qm_ = pm[b * L_SEQ + q_]; \
        const float r8_ = qm_ / lsum_; \
        const size_t off_ = (size_t)b * LM + (size_t)q_ * NM + c * 8 + g * 4; \
        float4 xv_ = *(const float4*)&x[off_]; \
        float4 o_ = make_float4(fmaf(oacc_[0], r8_, xv_.x), fmaf(oacc_[1], r8_, xv_.y), \
                                fmaf(oacc_[2], r8_, xv_.z), fmaf(oacc_[3], r8_, xv_.w)); \
        *(float4*)&out[off_] = o_; \
    } \
} while (0)

        RUNPASS(qfLo, qlo);
        RUNPASS(qfHi, qhi);
#undef RUNPASS
#undef ACHUNK2
    } else {
        // ---------------- out2: attention[b][k] = qm(b,1023)/8 * sum_c softmax_row_c[k] ----------
        const int b = u;
        float* red = (float*)Kl;
        const float qm = pm[b * L_SEQ + 1023];
        const float sc = RS8 * LOG2E;
        float acc[4] = {0.f, 0.f, 0.f, 0.f};
        float* out2 = out + BLM;
        for (int cc = 0; cc < 8; cc++) {
            const size_t hoff = (size_t)(b * 8 + cc) * 8192;
            us8 qv = *(const us8*)&H[hoff + (size_t)1023 * 8];
            const float q0 = bf2f(qv[0]) * sc, q1 = bf2f(qv[1]) * sc;
            const float q2 = bf2f(qv[2]) * sc, q3 = bf2f(qv[3]) * sc;
            const float q4 = bf2f(qv[4]) * sc, q5 = bf2f(qv[5]) * sc;
            const float q6 = bf2f(qv[6]) * sc, q7 = bf2f(qv[7]) * sc;
            const u16* Kg = H + 524288 + hoff;
            float p[4];
            float ts = 0.f;
#pragma unroll
            for (int i = 0; i < 4; i++) {
                int k = tid + 256 * i;
                us8 kv = *(const us8*)&Kg[(size_t)k * 8];
                float sa = fmaf(q0, bf2f(kv[0]), fmaf(q1, bf2f(kv[1]), fmaf(q2, bf2f(kv[2]), q3 * bf2f(kv[3]))));
                float sb = fmaf(q4, bf2f(kv[4]), fmaf(q5, bf2f(kv[5]), fmaf(q6, bf2f(kv[6]), q7 * bf2f(kv[7]))));
                p[i] = exp2f(sa + sb);
                ts += p[i];
            }
            ts = wredsum(ts);
            if (lane == 0) red[wv] = ts;
            __syncthreads();
            const float inv = 0.125f / (red[0] + red[1] + red[2] + red[3]);
            __syncthreads();
#pragma unroll
            for (int i = 0; i < 4; i++) acc[i] = fmaf(p[i], inv, acc[i]);
        }
#pragma unroll
        for (int i = 0; i < 4; i++) out2[b * L_SEQ + tid + 256 * i] = acc[i] * qm;
    }
}

extern "C" void kernel_launch(void* const* d_in, const int* in_sizes, int n_in,
                              void* d_out, int out_size, void* d_ws, size_t ws_size,
                              hipStream_t stream) {
    const float* x  = (const float*)d_in[0];
    const float* pm = (const float*)d_in[1];
    const float* Wq = (const float*)d_in[2];
    const float* Wk = (const float*)d_in[3];
    const float* Wv = (const float*)d_in[4];

    u16* H    = (u16*)d_ws;                              // 3 MB bf16 head-major Q,K,V
    u16* Wbf  = (u16*)((char*)d_ws + 3145728);           // 6 MB bf16 W[3][1024][1024]
    u16* xT   = (u16*)((char*)d_ws + 9437184);           // 1 MB bf16 xT[8][64][1024]
    u16* VtG  = (u16*)((char*)d_ws + 10485760);          // 1 MB bf16 Vt[64 heads][8][1024]
    float* out = (float*)d_out;                          // [8,1024,64] then [8,1024]

    hipLaunchKernelGGL(prep_kernel, dim3(1664), dim3(256), 0, stream, x, Wq, Wk, Wv, Wbf, xT);
    hipLaunchKernelGGL(proj_mfma, dim3(8, 32, 3), dim3(256), 0, stream, Wbf, xT, H, VtG);
    hipLaunchKernelGGL(attn_mfma, dim3(520), dim3(256), 0, stream, H, VtG, x, pm, out);
}